// Round 1
// baseline (45413.089 us; speedup 1.0000x reference)
//
#include <hip/hip_runtime.h>

#define NB 4096     // batch per branch
#define NF 58       // input features
#define NTIME 30    // timesteps
#define H1 512
#define H2 128
#define H3 64
#define BT 8        // batch rows per workgroup
#define NT 512      // threads per workgroup
#define NWG ((2 * NB) / BT)   // 1024 workgroups (both branches)

__device__ __forceinline__ float sigf(float x) {
    return 1.0f / (1.0f + __expf(-x));
}
__device__ __forceinline__ float tanhfast(float x) {
    // tanh(x) = 1 - 2/(exp(2x)+1); saturates correctly at +/-1 for large |x|
    return 1.0f - 2.0f / (__expf(2.0f * x) + 1.0f);
}

// Fused 3-layer LSTM over all T=30 steps. Grid: NWG x NT.
// Thread mapping: lb = tid & 7 (batch row in tile), hg = tid >> 3 (0..63).
// L1: 8 hidden units per thread; L2: 2; L3: 1. Cell state c lives in registers
// (unit loops fully unrolled -> constant indexing). h state double-buffered in LDS.
__global__ __launch_bounds__(NT) void lstm3_kernel(
    const float* __restrict__ x1, const float* __restrict__ x2,
    const float* __restrict__ Wih1, const float* __restrict__ Whh1, const float* __restrict__ b1,
    const float* __restrict__ Wih2, const float* __restrict__ Whh2, const float* __restrict__ b2,
    const float* __restrict__ Wih3, const float* __restrict__ Whh3, const float* __restrict__ b3,
    float* __restrict__ Y3)
{
    // +4 pad: keeps rows 16B-aligned for ds_read_b128 and gives 2-way-max bank aliasing (free)
    __shared__ __align__(16) float h1s[2][BT][H1 + 4];
    __shared__ __align__(16) float h2s[2][BT][H2 + 4];
    __shared__ __align__(16) float h3s[2][BT][H3 + 4];
    __shared__ __align__(16) float xs[BT][NF + 2];

    const int tid = threadIdx.x;
    const int lb  = tid & (BT - 1);
    const int hg  = tid >> 3;              // 0..63
    const int wg  = blockIdx.x;
    const float* __restrict__ Xp = (wg < (NWG / 2)) ? x1 : x2;
    const int row0 = (wg & (NWG / 2 - 1)) * BT;   // sample base within branch
    const int gr0  = wg * BT;                     // global output row base (0..8191)

    // zero h-state LDS
    {
        float* p = &h1s[0][0][0];
        for (int i = tid; i < 2 * BT * (H1 + 4); i += NT) p[i] = 0.0f;
        p = &h2s[0][0][0];
        for (int i = tid; i < 2 * BT * (H2 + 4); i += NT) p[i] = 0.0f;
        p = &h3s[0][0][0];
        for (int i = tid; i < 2 * BT * (H3 + 4); i += NT) p[i] = 0.0f;
    }
    float c1r[8];
    float c2r[2];
    float c3r;
    #pragma unroll
    for (int j = 0; j < 8; ++j) c1r[j] = 0.0f;
    c2r[0] = 0.0f; c2r[1] = 0.0f;
    c3r = 0.0f;
    __syncthreads();

    int cur = 0;
    for (int t = 0; t < NTIME; ++t) {
        const int nxt = cur ^ 1;

        // stage x_t: xs[b][f] = X[row0+b][f][t]   (input layout [B, F, T])
        for (int e = tid; e < BT * NF; e += NT) {
            const int b = e / NF;
            const int f = e - b * NF;
            xs[b][f] = Xp[(row0 + b) * (NF * NTIME) + f * NTIME + t];
        }
        __syncthreads();

        // ================= layer 1 (58 -> 512) =================
        #pragma unroll
        for (int j = 0; j < 8; ++j) {
            const int u = hg * 8 + j;
            float ai = b1[u];
            float af = b1[H1 + u];
            float ag = b1[2 * H1 + u];
            float ao = b1[3 * H1 + u];
            {   // input contribution (scalar, rows are 58 floats)
                const float* wi = Wih1 + u * NF;
                const float* wf = Wih1 + (H1 + u) * NF;
                const float* wg_ = Wih1 + (2 * H1 + u) * NF;
                const float* wo = Wih1 + (3 * H1 + u) * NF;
                #pragma unroll 2
                for (int f = 0; f < NF; ++f) {
                    const float xv = xs[lb][f];
                    ai = fmaf(xv, wi[f], ai);
                    af = fmaf(xv, wf[f], af);
                    ag = fmaf(xv, wg_[f], ag);
                    ao = fmaf(xv, wo[f], ao);
                }
            }
            {   // recurrent contribution (float4 over k)
                const float4* wi = (const float4*)(Whh1 + u * H1);
                const float4* wf = (const float4*)(Whh1 + (H1 + u) * H1);
                const float4* wg_ = (const float4*)(Whh1 + (2 * H1 + u) * H1);
                const float4* wo = (const float4*)(Whh1 + (3 * H1 + u) * H1);
                const float4* hv = (const float4*)(&h1s[cur][lb][0]);
                #pragma unroll 4
                for (int kc = 0; kc < H1 / 4; ++kc) {
                    const float4 h4 = hv[kc];
                    const float4 a4 = wi[kc];
                    const float4 b4 = wf[kc];
                    const float4 g4 = wg_[kc];
                    const float4 o4 = wo[kc];
                    ai += h4.x * a4.x + h4.y * a4.y + h4.z * a4.z + h4.w * a4.w;
                    af += h4.x * b4.x + h4.y * b4.y + h4.z * b4.z + h4.w * b4.w;
                    ag += h4.x * g4.x + h4.y * g4.y + h4.z * g4.z + h4.w * g4.w;
                    ao += h4.x * o4.x + h4.y * o4.y + h4.z * o4.z + h4.w * o4.w;
                }
            }
            const float iv = sigf(ai);
            const float fv = sigf(af);
            const float gv = tanhfast(ag);
            const float ov = sigf(ao);
            const float c = fv * c1r[j] + iv * gv;
            c1r[j] = c;
            h1s[nxt][lb][u] = ov * tanhfast(c);
        }
        __syncthreads();

        // ================= layer 2 (relu(h1) -> 128) =================
        #pragma unroll
        for (int j = 0; j < 2; ++j) {
            const int u = hg * 2 + j;
            float ai = b2[u];
            float af = b2[H2 + u];
            float ag = b2[2 * H2 + u];
            float ao = b2[3 * H2 + u];
            {   // input contribution: relu(h1s[nxt]) . Wih2 rows (512 cols)
                const float4* wi = (const float4*)(Wih2 + u * H1);
                const float4* wf = (const float4*)(Wih2 + (H2 + u) * H1);
                const float4* wg_ = (const float4*)(Wih2 + (2 * H2 + u) * H1);
                const float4* wo = (const float4*)(Wih2 + (3 * H2 + u) * H1);
                const float4* hv = (const float4*)(&h1s[nxt][lb][0]);
                #pragma unroll 4
                for (int kc = 0; kc < H1 / 4; ++kc) {
                    float4 h4 = hv[kc];
                    h4.x = fmaxf(h4.x, 0.0f);
                    h4.y = fmaxf(h4.y, 0.0f);
                    h4.z = fmaxf(h4.z, 0.0f);
                    h4.w = fmaxf(h4.w, 0.0f);
                    const float4 a4 = wi[kc];
                    const float4 b4 = wf[kc];
                    const float4 g4 = wg_[kc];
                    const float4 o4 = wo[kc];
                    ai += h4.x * a4.x + h4.y * a4.y + h4.z * a4.z + h4.w * a4.w;
                    af += h4.x * b4.x + h4.y * b4.y + h4.z * b4.z + h4.w * b4.w;
                    ag += h4.x * g4.x + h4.y * g4.y + h4.z * g4.z + h4.w * g4.w;
                    ao += h4.x * o4.x + h4.y * o4.y + h4.z * o4.z + h4.w * o4.w;
                }
            }
            {   // recurrent contribution (128 cols)
                const float4* wi = (const float4*)(Whh2 + u * H2);
                const float4* wf = (const float4*)(Whh2 + (H2 + u) * H2);
                const float4* wg_ = (const float4*)(Whh2 + (2 * H2 + u) * H2);
                const float4* wo = (const float4*)(Whh2 + (3 * H2 + u) * H2);
                const float4* hv = (const float4*)(&h2s[cur][lb][0]);
                #pragma unroll 4
                for (int kc = 0; kc < H2 / 4; ++kc) {
                    const float4 h4 = hv[kc];
                    const float4 a4 = wi[kc];
                    const float4 b4 = wf[kc];
                    const float4 g4 = wg_[kc];
                    const float4 o4 = wo[kc];
                    ai += h4.x * a4.x + h4.y * a4.y + h4.z * a4.z + h4.w * a4.w;
                    af += h4.x * b4.x + h4.y * b4.y + h4.z * b4.z + h4.w * b4.w;
                    ag += h4.x * g4.x + h4.y * g4.y + h4.z * g4.z + h4.w * g4.w;
                    ao += h4.x * o4.x + h4.y * o4.y + h4.z * o4.z + h4.w * o4.w;
                }
            }
            const float iv = sigf(ai);
            const float fv = sigf(af);
            const float gv = tanhfast(ag);
            const float ov = sigf(ao);
            const float c = fv * c2r[j] + iv * gv;
            c2r[j] = c;
            h2s[nxt][lb][u] = ov * tanhfast(c);
        }
        __syncthreads();

        // ================= layer 3 (relu(h2) -> 64) =================
        {
            const int u = hg;   // 0..63, one unit per thread
            float ai = b3[u];
            float af = b3[H3 + u];
            float ag = b3[2 * H3 + u];
            float ao = b3[3 * H3 + u];
            {   // input contribution: relu(h2s[nxt]) . Wih3 rows (128 cols)
                const float4* wi = (const float4*)(Wih3 + u * H2);
                const float4* wf = (const float4*)(Wih3 + (H3 + u) * H2);
                const float4* wg_ = (const float4*)(Wih3 + (2 * H3 + u) * H2);
                const float4* wo = (const float4*)(Wih3 + (3 * H3 + u) * H2);
                const float4* hv = (const float4*)(&h2s[nxt][lb][0]);
                #pragma unroll 4
                for (int kc = 0; kc < H2 / 4; ++kc) {
                    float4 h4 = hv[kc];
                    h4.x = fmaxf(h4.x, 0.0f);
                    h4.y = fmaxf(h4.y, 0.0f);
                    h4.z = fmaxf(h4.z, 0.0f);
                    h4.w = fmaxf(h4.w, 0.0f);
                    const float4 a4 = wi[kc];
                    const float4 b4 = wf[kc];
                    const float4 g4 = wg_[kc];
                    const float4 o4 = wo[kc];
                    ai += h4.x * a4.x + h4.y * a4.y + h4.z * a4.z + h4.w * a4.w;
                    af += h4.x * b4.x + h4.y * b4.y + h4.z * b4.z + h4.w * b4.w;
                    ag += h4.x * g4.x + h4.y * g4.y + h4.z * g4.z + h4.w * g4.w;
                    ao += h4.x * o4.x + h4.y * o4.y + h4.z * o4.z + h4.w * o4.w;
                }
            }
            {   // recurrent contribution (64 cols)
                const float4* wi = (const float4*)(Whh3 + u * H3);
                const float4* wf = (const float4*)(Whh3 + (H3 + u) * H3);
                const float4* wg_ = (const float4*)(Whh3 + (2 * H3 + u) * H3);
                const float4* wo = (const float4*)(Whh3 + (3 * H3 + u) * H3);
                const float4* hv = (const float4*)(&h3s[cur][lb][0]);
                #pragma unroll 4
                for (int kc = 0; kc < H3 / 4; ++kc) {
                    const float4 h4 = hv[kc];
                    const float4 a4 = wi[kc];
                    const float4 b4 = wf[kc];
                    const float4 g4 = wg_[kc];
                    const float4 o4 = wo[kc];
                    ai += h4.x * a4.x + h4.y * a4.y + h4.z * a4.z + h4.w * a4.w;
                    af += h4.x * b4.x + h4.y * b4.y + h4.z * b4.z + h4.w * b4.w;
                    ag += h4.x * g4.x + h4.y * g4.y + h4.z * g4.z + h4.w * g4.w;
                    ao += h4.x * o4.x + h4.y * o4.y + h4.z * o4.z + h4.w * o4.w;
                }
            }
            const float iv = sigf(ai);
            const float fv = sigf(af);
            const float gv = tanhfast(ag);
            const float ov = sigf(ao);
            const float c = fv * c3r + iv * gv;
            c3r = c;
            const float h = ov * tanhfast(c);
            h3s[nxt][lb][u] = h;
            Y3[(gr0 + lb) * (NTIME * H3) + t * H3 + u] = fmaxf(h, 0.0f);
        }
        __syncthreads();
        cur = nxt;
    }
}

// FC head: d = |Y3[b] - Y3[b+4096]| (1920) -> 960 -> 480 -> 16 -> 1
#define BTH 4
__global__ __launch_bounds__(256) void head_kernel(
    const float* __restrict__ Y3,
    const float* __restrict__ Wf1, const float* __restrict__ bf1,
    const float* __restrict__ Wf2, const float* __restrict__ bf2,
    const float* __restrict__ Wf3, const float* __restrict__ bf3,
    const float* __restrict__ Wf4, const float* __restrict__ bf4,
    float* __restrict__ out)
{
    __shared__ __align__(16) float ds[BTH][1924];
    __shared__ __align__(16) float a1[BTH][964];
    __shared__ __align__(16) float a2[BTH][484];
    __shared__ __align__(16) float a3[BTH][16];

    const int tid = threadIdx.x;
    const int wg  = blockIdx.x;
    const int r0  = wg * BTH;

    // stage |h1 - h2|
    for (int e = tid; e < BTH * 1920; e += 256) {
        const int b = e / 1920;
        const int j = e - b * 1920;
        const float v1 = Y3[(r0 + b) * 1920 + j];
        const float v2 = Y3[(r0 + b + NB) * 1920 + j];
        ds[b][j] = fabsf(v1 - v2);
    }
    __syncthreads();

    const int lb = tid & (BTH - 1);
    const int og = tid >> 2;   // 0..63

    // fc1: 1920 -> 960, relu
    for (int m = 0; m < 15; ++m) {
        const int o = og + 64 * m;
        float acc = bf1[o];
        const float4* wr = (const float4*)(Wf1 + (size_t)o * 1920);
        const float4* dv = (const float4*)(&ds[lb][0]);
        #pragma unroll 4
        for (int kc = 0; kc < 480; ++kc) {
            const float4 d4 = dv[kc];
            const float4 w4 = wr[kc];
            acc += d4.x * w4.x + d4.y * w4.y + d4.z * w4.z + d4.w * w4.w;
        }
        a1[lb][o] = fmaxf(acc, 0.0f);
    }
    __syncthreads();

    // fc2: 960 -> 480, relu
    for (int m = 0; m < 8; ++m) {
        const int o = og + 64 * m;
        if (o < 480) {
            float acc = bf2[o];
            const float4* wr = (const float4*)(Wf2 + (size_t)o * 960);
            const float4* av = (const float4*)(&a1[lb][0]);
            #pragma unroll 4
            for (int kc = 0; kc < 240; ++kc) {
                const float4 d4 = av[kc];
                const float4 w4 = wr[kc];
                acc += d4.x * w4.x + d4.y * w4.y + d4.z * w4.z + d4.w * w4.w;
            }
            a2[lb][o] = fmaxf(acc, 0.0f);
        }
    }
    __syncthreads();

    // fc3: 480 -> 16, relu
    if (tid < 64) {
        const int o = tid >> 2;      // 0..15
        const int b = tid & (BTH - 1);
        float acc = bf3[o];
        const float4* wr = (const float4*)(Wf3 + (size_t)o * 480);
        const float4* av = (const float4*)(&a2[b][0]);
        #pragma unroll 4
        for (int kc = 0; kc < 120; ++kc) {
            const float4 d4 = av[kc];
            const float4 w4 = wr[kc];
            acc += d4.x * w4.x + d4.y * w4.y + d4.z * w4.z + d4.w * w4.w;
        }
        a3[b][o] = fmaxf(acc, 0.0f);
    }
    __syncthreads();

    // fc4: 16 -> 1
    if (tid < BTH) {
        float acc = bf4[0];
        #pragma unroll
        for (int k = 0; k < 16; ++k) acc += a3[tid][k] * Wf4[k];
        out[r0 + tid] = acc;
    }
}

extern "C" void kernel_launch(void* const* d_in, const int* in_sizes, int n_in,
                              void* d_out, int out_size, void* d_ws, size_t ws_size,
                              hipStream_t stream) {
    const float* x1   = (const float*)d_in[0];
    const float* x2   = (const float*)d_in[1];
    const float* Wih1 = (const float*)d_in[2];
    const float* Whh1 = (const float*)d_in[3];
    const float* b1   = (const float*)d_in[4];
    const float* Wih2 = (const float*)d_in[5];
    const float* Whh2 = (const float*)d_in[6];
    const float* b2   = (const float*)d_in[7];
    const float* Wih3 = (const float*)d_in[8];
    const float* Whh3 = (const float*)d_in[9];
    const float* b3   = (const float*)d_in[10];
    const float* Wf1  = (const float*)d_in[11];
    const float* bf1  = (const float*)d_in[12];
    const float* Wf2  = (const float*)d_in[13];
    const float* bf2  = (const float*)d_in[14];
    const float* Wf3  = (const float*)d_in[15];
    const float* bf3  = (const float*)d_in[16];
    const float* Wf4  = (const float*)d_in[17];
    const float* bf4  = (const float*)d_in[18];

    float* Y3  = (float*)d_ws;   // [8192][30][64] fp32 = 63 MB
    float* out = (float*)d_out;  // [4096][1]

    lstm3_kernel<<<NWG, NT, 0, stream>>>(x1, x2, Wih1, Whh1, b1,
                                         Wih2, Whh2, b2, Wih3, Whh3, b3, Y3);
    head_kernel<<<NB / BTH, 256, 0, stream>>>(Y3, Wf1, bf1, Wf2, bf2,
                                              Wf3, bf3, Wf4, bf4, out);
}

// Round 2
// 16249.342 us; speedup vs baseline: 2.7948x; 2.7948x over previous
//
#include <hip/hip_runtime.h>

#define NB 4096     // batch per branch
#define NF 58
#define NFP 60      // NF padded to multiple of 4
#define NTIME 30
#define H1 512
#define H2 128
#define H3 64
#define BT 16       // batch rows per workgroup
#define NT 1024     // threads per workgroup
#define NWG 512     // (2*NB)/BT

__device__ __forceinline__ float sigf(float x) {
    return 1.0f / (1.0f + __expf(-x));
}
__device__ __forceinline__ float tanhfast(float x) {
    return 1.0f - 2.0f / (__expf(2.0f * x) + 1.0f);
}
__device__ __forceinline__ float4 relu4(const float4* p) {
    float4 v = *p;
    v.x = fmaxf(v.x, 0.0f); v.y = fmaxf(v.y, 0.0f);
    v.z = fmaxf(v.z, 0.0f); v.w = fmaxf(v.w, 0.0f);
    return v;
}

#define DOT4(A, X, W) { A = fmaf((X).x,(W).x,A); A = fmaf((X).y,(W).y,A); \
                        A = fmaf((X).z,(W).z,A); A = fmaf((X).w,(W).w,A); }

// W[g*H+u][K] row-major -> WT[((g*(KP/4)+kc)*H + u)*4 + kk]; zero-pad k>=K.
// Makes lane-consecutive units contiguous: a wave's float4 weight load is 1KB coalesced.
__global__ void transpose_w(const float* __restrict__ W, float* __restrict__ WT,
                            int H, int K, int KP)
{
    int e = blockIdx.x * 256 + threadIdx.x;
    int total = 4 * H * KP;
    if (e >= total) return;
    int kk = e & 3;
    int t1 = e >> 2;
    int u  = t1 % H;
    int t2 = t1 / H;
    int kc4 = KP >> 2;
    int kc = t2 % kc4;
    int g  = t2 / kc4;
    int k  = kc * 4 + kk;
    WT[e] = (k < K) ? W[(g * H + u) * K + k] : 0.0f;
}

// Fused 3-layer LSTM, all 30 steps. 1024 threads, 16 batch rows/WG.
// L1: thread = (unit u1<512, row-group rg1<2 of 8 rows) -> 32 accumulators.
// L2: thread = (u2<128, 2 rows).  L3: thread = (u3<64, 1 row).
// Weight loads: lane-coalesced float4 (transposed layout), each reused across rows.
// h reads: wave-uniform LDS broadcast (free). h1 single-buffered, h2/h3 double.
__global__ __launch_bounds__(NT) void lstm3_kernel(
    const float* __restrict__ x1, const float* __restrict__ x2,
    const float* __restrict__ WT1ih, const float* __restrict__ WT1hh, const float* __restrict__ b1,
    const float* __restrict__ WT2ih, const float* __restrict__ WT2hh, const float* __restrict__ b2,
    const float* __restrict__ WT3ih, const float* __restrict__ WT3hh, const float* __restrict__ b3,
    float* __restrict__ Y3)
{
    __shared__ __align__(16) float xs[BT][64];
    __shared__ __align__(16) float h1s[BT][H1 + 4];
    __shared__ __align__(16) float h2s[2][BT][H2 + 4];
    __shared__ __align__(16) float h3s[2][BT][H3 + 4];

    const int tid = threadIdx.x;
    const int wg  = blockIdx.x;
    const float* __restrict__ Xp = (wg < 256) ? x1 : x2;
    const int row0 = (wg & 255) * BT;
    const int gr0  = wg * BT;

    const int u1  = tid & (H1 - 1);
    const int r10 = (tid >> 9) * 8;     // 0 or 8
    const int u2  = tid & (H2 - 1);
    const int r20 = (tid >> 7) * 2;     // 0,2,..,14
    const int u3  = tid & (H3 - 1);
    const int r3  = tid >> 6;           // 0..15

    for (int i = tid; i < BT * (H1 + 4); i += NT) (&h1s[0][0])[i] = 0.0f;
    for (int i = tid; i < 2 * BT * (H2 + 4); i += NT) (&h2s[0][0][0])[i] = 0.0f;
    for (int i = tid; i < 2 * BT * (H3 + 4); i += NT) (&h3s[0][0][0])[i] = 0.0f;

    float c1[8];
    #pragma unroll
    for (int r = 0; r < 8; ++r) c1[r] = 0.0f;
    float c2[2] = {0.0f, 0.0f};
    float c3 = 0.0f;

    float bi1[4], bi2[4], bi3[4];
    #pragma unroll
    for (int g = 0; g < 4; ++g) {
        bi1[g] = b1[g * H1 + u1];
        bi2[g] = b2[g * H2 + u2];
        bi3[g] = b3[g * H3 + u3];
    }

    const float4* W1i = (const float4*)WT1ih;   // [(g*15 +kc)*512 + u]
    const float4* W1h = (const float4*)WT1hh;   // [(g*128+kc)*512 + u]
    const float4* W2i = (const float4*)WT2ih;   // [(g*128+kc)*128 + u]
    const float4* W2h = (const float4*)WT2hh;   // [(g*32 +kc)*128 + u]
    const float4* W3i = (const float4*)WT3ih;   // [(g*32 +kc)*64  + u]
    const float4* W3h = (const float4*)WT3hh;   // [(g*16 +kc)*64  + u]

    __syncthreads();

    int cur = 0;
    for (int t = 0; t < NTIME; ++t) {
        const int nxt = cur ^ 1;

        // stage x_t (input layout [B, F, T])
        if (tid < BT * NFP) {
            const int b = tid / NFP;
            const int f = tid - b * NFP;
            xs[b][f] = (f < NF) ? Xp[(row0 + b) * (NF * NTIME) + f * NTIME + t] : 0.0f;
        }
        __syncthreads();   // A: xs staged; h1s/h2s/h3s from prev step visible

        // ================= layer 1 (58 -> 512) =================
        float a1g[8][4];
        #pragma unroll
        for (int r = 0; r < 8; ++r)
            #pragma unroll
            for (int g = 0; g < 4; ++g) a1g[r][g] = bi1[g];

        #pragma unroll 3
        for (int kc = 0; kc < NFP / 4; ++kc) {
            const float4 w0 = W1i[(0 * 15 + kc) * H1 + u1];
            const float4 w1 = W1i[(1 * 15 + kc) * H1 + u1];
            const float4 w2 = W1i[(2 * 15 + kc) * H1 + u1];
            const float4 w3 = W1i[(3 * 15 + kc) * H1 + u1];
            #pragma unroll
            for (int r = 0; r < 8; ++r) {
                const float4 xv = *(const float4*)&xs[r10 + r][kc * 4];
                DOT4(a1g[r][0], xv, w0);
                DOT4(a1g[r][1], xv, w1);
                DOT4(a1g[r][2], xv, w2);
                DOT4(a1g[r][3], xv, w3);
            }
        }
        #pragma unroll 2
        for (int kc = 0; kc < H1 / 4; ++kc) {
            const float4 w0 = W1h[(0 * 128 + kc) * H1 + u1];
            const float4 w1 = W1h[(1 * 128 + kc) * H1 + u1];
            const float4 w2 = W1h[(2 * 128 + kc) * H1 + u1];
            const float4 w3 = W1h[(3 * 128 + kc) * H1 + u1];
            #pragma unroll
            for (int r = 0; r < 8; ++r) {
                const float4 hv = *(const float4*)&h1s[r10 + r][kc * 4];
                DOT4(a1g[r][0], hv, w0);
                DOT4(a1g[r][1], hv, w1);
                DOT4(a1g[r][2], hv, w2);
                DOT4(a1g[r][3], hv, w3);
            }
        }
        float h1n[8];
        #pragma unroll
        for (int r = 0; r < 8; ++r) {
            const float iv = sigf(a1g[r][0]);
            const float fv = sigf(a1g[r][1]);
            const float gv = tanhfast(a1g[r][2]);
            const float ov = sigf(a1g[r][3]);
            c1[r] = fv * c1[r] + iv * gv;
            h1n[r] = ov * tanhfast(c1[r]);
        }
        __syncthreads();   // B: all reads of h1s(old) done
        #pragma unroll
        for (int r = 0; r < 8; ++r) h1s[r10 + r][u1] = h1n[r];
        __syncthreads();   // C: h1s(new) visible

        // ================= layer 2 (relu(h1) -> 128) =================
        float a2g[2][4];
        #pragma unroll
        for (int r = 0; r < 2; ++r)
            #pragma unroll
            for (int g = 0; g < 4; ++g) a2g[r][g] = bi2[g];

        #pragma unroll 2
        for (int kc = 0; kc < H1 / 4; ++kc) {
            const float4 w0 = W2i[(0 * 128 + kc) * H2 + u2];
            const float4 w1 = W2i[(1 * 128 + kc) * H2 + u2];
            const float4 w2 = W2i[(2 * 128 + kc) * H2 + u2];
            const float4 w3 = W2i[(3 * 128 + kc) * H2 + u2];
            #pragma unroll
            for (int r = 0; r < 2; ++r) {
                const float4 hv = relu4((const float4*)&h1s[r20 + r][kc * 4]);
                DOT4(a2g[r][0], hv, w0);
                DOT4(a2g[r][1], hv, w1);
                DOT4(a2g[r][2], hv, w2);
                DOT4(a2g[r][3], hv, w3);
            }
        }
        #pragma unroll 2
        for (int kc = 0; kc < H2 / 4; ++kc) {
            const float4 w0 = W2h[(0 * 32 + kc) * H2 + u2];
            const float4 w1 = W2h[(1 * 32 + kc) * H2 + u2];
            const float4 w2 = W2h[(2 * 32 + kc) * H2 + u2];
            const float4 w3 = W2h[(3 * 32 + kc) * H2 + u2];
            #pragma unroll
            for (int r = 0; r < 2; ++r) {
                const float4 hv = *(const float4*)&h2s[cur][r20 + r][kc * 4];
                DOT4(a2g[r][0], hv, w0);
                DOT4(a2g[r][1], hv, w1);
                DOT4(a2g[r][2], hv, w2);
                DOT4(a2g[r][3], hv, w3);
            }
        }
        #pragma unroll
        for (int r = 0; r < 2; ++r) {
            const float iv = sigf(a2g[r][0]);
            const float fv = sigf(a2g[r][1]);
            const float gv = tanhfast(a2g[r][2]);
            const float ov = sigf(a2g[r][3]);
            c2[r] = fv * c2[r] + iv * gv;
            h2s[nxt][r20 + r][u2] = ov * tanhfast(c2[r]);
        }
        __syncthreads();   // D: h2s(new) visible

        // ================= layer 3 (relu(h2) -> 64) =================
        float a3g[4];
        #pragma unroll
        for (int g = 0; g < 4; ++g) a3g[g] = bi3[g];

        #pragma unroll 2
        for (int kc = 0; kc < H2 / 4; ++kc) {
            const float4 w0 = W3i[(0 * 32 + kc) * H3 + u3];
            const float4 w1 = W3i[(1 * 32 + kc) * H3 + u3];
            const float4 w2 = W3i[(2 * 32 + kc) * H3 + u3];
            const float4 w3 = W3i[(3 * 32 + kc) * H3 + u3];
            const float4 hv = relu4((const float4*)&h2s[nxt][r3][kc * 4]);
            DOT4(a3g[0], hv, w0);
            DOT4(a3g[1], hv, w1);
            DOT4(a3g[2], hv, w2);
            DOT4(a3g[3], hv, w3);
        }
        #pragma unroll 2
        for (int kc = 0; kc < H3 / 4; ++kc) {
            const float4 w0 = W3h[(0 * 16 + kc) * H3 + u3];
            const float4 w1 = W3h[(1 * 16 + kc) * H3 + u3];
            const float4 w2 = W3h[(2 * 16 + kc) * H3 + u3];
            const float4 w3 = W3h[(3 * 16 + kc) * H3 + u3];
            const float4 hv = *(const float4*)&h3s[cur][r3][kc * 4];
            DOT4(a3g[0], hv, w0);
            DOT4(a3g[1], hv, w1);
            DOT4(a3g[2], hv, w2);
            DOT4(a3g[3], hv, w3);
        }
        {
            const float iv = sigf(a3g[0]);
            const float fv = sigf(a3g[1]);
            const float gv = tanhfast(a3g[2]);
            const float ov = sigf(a3g[3]);
            c3 = fv * c3 + iv * gv;
            const float h = ov * tanhfast(c3);
            h3s[nxt][r3][u3] = h;
            Y3[(gr0 + r3) * (NTIME * H3) + t * H3 + u3] = fmaxf(h, 0.0f);
        }
        cur = nxt;
        // no sync here: top-of-loop sync A orders h3s/h1s/h2s hazards
    }
}

// FC head: d = |Y3[b] - Y3[b+4096]| (1920) -> 960 -> 480 -> 16 -> 1
#define BTH 4
__global__ __launch_bounds__(256) void head_kernel(
    const float* __restrict__ Y3,
    const float* __restrict__ Wf1, const float* __restrict__ bf1,
    const float* __restrict__ Wf2, const float* __restrict__ bf2,
    const float* __restrict__ Wf3, const float* __restrict__ bf3,
    const float* __restrict__ Wf4, const float* __restrict__ bf4,
    float* __restrict__ out)
{
    __shared__ __align__(16) float ds[BTH][1924];
    __shared__ __align__(16) float a1[BTH][964];
    __shared__ __align__(16) float a2[BTH][484];
    __shared__ __align__(16) float a3[BTH][16];

    const int tid = threadIdx.x;
    const int r0  = blockIdx.x * BTH;

    for (int e = tid; e < BTH * 1920; e += 256) {
        const int b = e / 1920;
        const int j = e - b * 1920;
        const float v1 = Y3[(r0 + b) * 1920 + j];
        const float v2 = Y3[(r0 + b + NB) * 1920 + j];
        ds[b][j] = fabsf(v1 - v2);
    }
    __syncthreads();

    const int lb = tid & (BTH - 1);
    const int og = tid >> 2;

    for (int m = 0; m < 15; ++m) {
        const int o = og + 64 * m;
        float acc = bf1[o];
        const float4* wr = (const float4*)(Wf1 + (size_t)o * 1920);
        const float4* dv = (const float4*)(&ds[lb][0]);
        #pragma unroll 4
        for (int kc = 0; kc < 480; ++kc) {
            const float4 d4 = dv[kc];
            const float4 w4 = wr[kc];
            acc += d4.x * w4.x + d4.y * w4.y + d4.z * w4.z + d4.w * w4.w;
        }
        a1[lb][o] = fmaxf(acc, 0.0f);
    }
    __syncthreads();

    for (int m = 0; m < 8; ++m) {
        const int o = og + 64 * m;
        if (o < 480) {
            float acc = bf2[o];
            const float4* wr = (const float4*)(Wf2 + (size_t)o * 960);
            const float4* av = (const float4*)(&a1[lb][0]);
            #pragma unroll 4
            for (int kc = 0; kc < 240; ++kc) {
                const float4 d4 = av[kc];
                const float4 w4 = wr[kc];
                acc += d4.x * w4.x + d4.y * w4.y + d4.z * w4.z + d4.w * w4.w;
            }
            a2[lb][o] = fmaxf(acc, 0.0f);
        }
    }
    __syncthreads();

    if (tid < 64) {
        const int o = tid >> 2;
        const int b = tid & (BTH - 1);
        float acc = bf3[o];
        const float4* wr = (const float4*)(Wf3 + (size_t)o * 480);
        const float4* av = (const float4*)(&a2[b][0]);
        #pragma unroll 4
        for (int kc = 0; kc < 120; ++kc) {
            const float4 d4 = av[kc];
            const float4 w4 = wr[kc];
            acc += d4.x * w4.x + d4.y * w4.y + d4.z * w4.z + d4.w * w4.w;
        }
        a3[b][o] = fmaxf(acc, 0.0f);
    }
    __syncthreads();

    if (tid < BTH) {
        float acc = bf4[0];
        #pragma unroll
        for (int k = 0; k < 16; ++k) acc += a3[tid][k] * Wf4[k];
        out[r0 + tid] = acc;
    }
}

extern "C" void kernel_launch(void* const* d_in, const int* in_sizes, int n_in,
                              void* d_out, int out_size, void* d_ws, size_t ws_size,
                              hipStream_t stream) {
    const float* x1   = (const float*)d_in[0];
    const float* x2   = (const float*)d_in[1];
    const float* Wih1 = (const float*)d_in[2];
    const float* Whh1 = (const float*)d_in[3];
    const float* b1   = (const float*)d_in[4];
    const float* Wih2 = (const float*)d_in[5];
    const float* Whh2 = (const float*)d_in[6];
    const float* b2   = (const float*)d_in[7];
    const float* Wih3 = (const float*)d_in[8];
    const float* Whh3 = (const float*)d_in[9];
    const float* b3   = (const float*)d_in[10];
    const float* Wf1  = (const float*)d_in[11];
    const float* bf1  = (const float*)d_in[12];
    const float* Wf2  = (const float*)d_in[13];
    const float* bf2  = (const float*)d_in[14];
    const float* Wf3  = (const float*)d_in[15];
    const float* bf3  = (const float*)d_in[16];
    const float* Wf4  = (const float*)d_in[17];
    const float* bf4  = (const float*)d_in[18];

    float* ws = (float*)d_ws;
    float* Y3    = ws;                    // 8192*30*64 = 15,728,640 floats
    float* WT1ih = Y3    + 15728640;      // 4*512*60   = 122,880
    float* WT1hh = WT1ih + 122880;        // 4*512*512  = 1,048,576
    float* WT2ih = WT1hh + 1048576;       // 4*128*512  = 262,144
    float* WT2hh = WT2ih + 262144;        // 4*128*128  = 65,536
    float* WT3ih = WT2hh + 65536;         // 4*64*128   = 32,768
    float* WT3hh = WT3ih + 32768;         // 4*64*64    = 16,384
    float* out = (float*)d_out;

    transpose_w<<<(4 * 512 * 60  + 255) / 256, 256, 0, stream>>>(Wih1, WT1ih, 512, 58, 60);
    transpose_w<<<(4 * 512 * 512 + 255) / 256, 256, 0, stream>>>(Whh1, WT1hh, 512, 512, 512);
    transpose_w<<<(4 * 128 * 512 + 255) / 256, 256, 0, stream>>>(Wih2, WT2ih, 128, 512, 512);
    transpose_w<<<(4 * 128 * 128 + 255) / 256, 256, 0, stream>>>(Whh2, WT2hh, 128, 128, 128);
    transpose_w<<<(4 * 64 * 128 + 255) / 256, 256, 0, stream>>>(Wih3, WT3ih, 64, 128, 128);
    transpose_w<<<(4 * 64 * 64  + 255) / 256, 256, 0, stream>>>(Whh3, WT3hh, 64, 64, 64);

    lstm3_kernel<<<NWG, NT, 0, stream>>>(x1, x2, WT1ih, WT1hh, b1,
                                         WT2ih, WT2hh, b2, WT3ih, WT3hh, b3, Y3);
    head_kernel<<<NB / BTH, 256, 0, stream>>>(Y3, Wf1, bf1, Wf2, bf2,
                                              Wf3, bf3, Wf4, bf4, out);
}

// Round 3
// 5403.524 us; speedup vs baseline: 8.4043x; 3.0072x over previous
//
#include <hip/hip_runtime.h>

#define NTIME 30
#define NB 4096

typedef __attribute__((ext_vector_type(8))) short short8;
typedef __attribute__((ext_vector_type(4))) float f32x4;

__device__ __forceinline__ unsigned short f2b(float f) {
    unsigned int u = __float_as_uint(f);
    u = u + 0x7FFFu + ((u >> 16) & 1u);        // RNE to bf16
    return (unsigned short)(u >> 16);
}
__device__ __forceinline__ float b2f(unsigned short s) {
    return __uint_as_float(((unsigned int)s) << 16);
}
__device__ __forceinline__ float sigf(float x)     { return 1.0f / (1.0f + __expf(-x)); }
__device__ __forceinline__ float tanhfast(float x) { return 1.0f - 2.0f / (__expf(2.0f * x) + 1.0f); }

// Pack W rows (gate-major, PyTorch i,f,g,o) into MFMA B-fragment stream, bf16 hi/lo planes.
// B-frag for 16x16x32: lane holds B[k = (lane>>4)*8 + j][n = lane&15], j=0..7.
// Block layout: out[(((ks*UG + ug)*4 + g)*2 + plane)*512 + lane*8 + j]  (ushorts)
// k axis = [K_ih (padded to KIp) ; K_hh].
__global__ void prep_w(const float* __restrict__ Wih, const float* __restrict__ Whh,
                       unsigned short* __restrict__ out,
                       int H, int KIr, int KIp, int KH, int UG, int KS)
{
    int e = blockIdx.x * 256 + threadIdx.x;
    int total = KS * UG * 4 * 2 * 512;
    if (e >= total) return;
    int j     = e & 7;
    int lane  = (e >> 3) & 63;
    int plane = (e >> 9) & 1;
    int g     = (e >> 10) & 3;
    int x     = e >> 12;
    int ug    = x % UG;
    int ks    = x / UG;
    int n = lane & 15, q = lane >> 4;
    int k   = ks * 32 + q * 8 + j;
    int row = g * H + ug * 16 + n;
    float w = 0.0f;
    if (k < KIp) { if (k < KIr) w = Wih[row * KIr + k]; }
    else         { w = Whh[row * KH + (k - KIp)]; }
    unsigned short hi = f2b(w);
    out[e] = plane ? f2b(w - b2f(hi)) : hi;
}

// Fused 3-layer LSTM, MFMA bf16 hi/lo (3-product split precision).
// 256 WGs x 512 thr (8 waves), BT=32 batch rows/WG, 1 WG/CU, 100KB dynamic LDS.
// Wave w: L1 tiles ug=4w..4w+3 x 4 gates x 2 Mtiles; L2 ug=w; L3 (mt=w>>2, ug=w&3).
__global__ __launch_bounds__(512) void lstm3_mfma(
    const float* __restrict__ x1, const float* __restrict__ x2,
    const unsigned short* __restrict__ l1w, const unsigned short* __restrict__ l2w,
    const unsigned short* __restrict__ l3w,
    const float* __restrict__ b1, const float* __restrict__ b2, const float* __restrict__ b3,
    float* __restrict__ Y3)
{
    extern __shared__ unsigned short sm[];
    unsigned short* h1hi = sm;                    // 32 rows x 520 (512 + 8 pad)
    unsigned short* h1lo = h1hi + 32 * 520;
    unsigned short* h2hi = h1lo + 32 * 520;       // 32 x 136
    unsigned short* h2lo = h2hi + 32 * 136;
    unsigned short* h3hi = h2lo + 32 * 136;       // 32 x 72
    unsigned short* h3lo = h3hi + 32 * 72;
    unsigned short* xhi  = h3lo + 32 * 72;        // 32 x 72
    unsigned short* xlo  = xhi  + 32 * 72;

    const int tid  = threadIdx.x;
    const int wv   = tid >> 6;          // wave 0..7
    const int lane = tid & 63;
    const int nrow = lane & 15;         // unit-in-tile (B/C cols) and batch-row (A rows)
    const int quad = lane >> 4;

    const int wg  = blockIdx.x;
    const float* __restrict__ Xp = (wg < 128) ? x1 : x2;
    const int row0 = (wg & 127) * 32;
    const int gr0  = wg * 32;

    // zero recurrent state in LDS
    {
        unsigned int* p = (unsigned int*)sm;
        const int nu32 = (2 * (32 * 520) + 2 * (32 * 136) + 2 * (32 * 72)) / 2;
        for (int i = tid; i < nu32; i += 512) p[i] = 0u;
    }

    // per-lane biases
    float b1v[4][4], b2v[4], b3v[4];
    #pragma unroll
    for (int i = 0; i < 4; ++i)
        #pragma unroll
        for (int g = 0; g < 4; ++g)
            b1v[i][g] = b1[g * 512 + (wv * 4 + i) * 16 + nrow];
    #pragma unroll
    for (int g = 0; g < 4; ++g) b2v[g] = b2[g * 128 + wv * 16 + nrow];
    #pragma unroll
    for (int g = 0; g < 4; ++g) b3v[g] = b3[g * 64 + (wv & 3) * 16 + nrow];

    float c1[2][4][4];
    float c2[2][4];
    float c3[4];
    #pragma unroll
    for (int mt = 0; mt < 2; ++mt)
        #pragma unroll
        for (int i = 0; i < 4; ++i)
            #pragma unroll
            for (int r = 0; r < 4; ++r) c1[mt][i][r] = 0.0f;
    #pragma unroll
    for (int mt = 0; mt < 2; ++mt)
        #pragma unroll
        for (int r = 0; r < 4; ++r) c2[mt][r] = 0.0f;
    #pragma unroll
    for (int r = 0; r < 4; ++r) c3[r] = 0.0f;

    const unsigned short* B1 = l1w + wv * 4 * 4096 + lane * 8;   // + ks*131072 + i*4096 + g*1024 (+512 lo)
    const unsigned short* B2 = l2w + wv * 4096 + lane * 8;       // + ks*32768 + g*1024
    const unsigned short* B3 = l3w + (wv & 3) * 4096 + lane * 8; // + ks*16384 + g*1024
    const int mt3 = wv >> 2;

    __syncthreads();

    #pragma unroll 1
    for (int t = 0; t < NTIME; ++t) {
        const bool rev = (t & 1);

        // stage x_t (layout [B,F=58,T=30]) as bf16 hi/lo, K padded to 64
        for (int e = tid; e < 32 * 64; e += 512) {
            int b = e >> 6, f = e & 63;
            float v = (f < 58) ? Xp[(row0 + b) * 1740 + f * 30 + t] : 0.0f;
            unsigned short hi = f2b(v);
            xhi[b * 72 + f] = hi;
            xlo[b * 72 + f] = f2b(v - b2f(hi));
        }
        __syncthreads();   // x staged; previous-step h writes visible

        // ================= L1 (k = [x 64 ; h1 512], 18 ksteps) =================
        f32x4 acc[2][4][4];
        #pragma unroll
        for (int mt = 0; mt < 2; ++mt)
            #pragma unroll
            for (int i = 0; i < 4; ++i)
                #pragma unroll
                for (int g = 0; g < 4; ++g) {
                    float b = b1v[i][g];
                    f32x4 v = {b, b, b, b};
                    acc[mt][i][g] = v;
                }

        #pragma unroll 1
        for (int kk = 0; kk < 18; ++kk) {
            int ks = rev ? (17 - kk) : kk;
            short8 ahi[2], alo[2];
            if (ks < 2) {
                int off = ks * 32 + quad * 8;
                ahi[0] = *(const short8*)(xhi + nrow * 72 + off);
                ahi[1] = *(const short8*)(xhi + (16 + nrow) * 72 + off);
                alo[0] = *(const short8*)(xlo + nrow * 72 + off);
                alo[1] = *(const short8*)(xlo + (16 + nrow) * 72 + off);
            } else {
                int off = (ks - 2) * 32 + quad * 8;
                ahi[0] = *(const short8*)(h1hi + nrow * 520 + off);
                ahi[1] = *(const short8*)(h1hi + (16 + nrow) * 520 + off);
                alo[0] = *(const short8*)(h1lo + nrow * 520 + off);
                alo[1] = *(const short8*)(h1lo + (16 + nrow) * 520 + off);
            }
            const unsigned short* bb = B1 + ks * 131072;
            #pragma unroll
            for (int i = 0; i < 4; ++i) {
                #pragma unroll
                for (int g = 0; g < 4; ++g) {
                    short8 bhi = *(const short8*)(bb + i * 4096 + g * 1024);
                    short8 blo = *(const short8*)(bb + i * 4096 + g * 1024 + 512);
                    #pragma unroll
                    for (int mt = 0; mt < 2; ++mt) {
                        acc[mt][i][g] = __builtin_amdgcn_mfma_f32_16x16x32_bf16(ahi[mt], bhi, acc[mt][i][g], 0, 0, 0);
                        acc[mt][i][g] = __builtin_amdgcn_mfma_f32_16x16x32_bf16(alo[mt], bhi, acc[mt][i][g], 0, 0, 0);
                        acc[mt][i][g] = __builtin_amdgcn_mfma_f32_16x16x32_bf16(ahi[mt], blo, acc[mt][i][g], 0, 0, 0);
                    }
                }
            }
        }
        __syncthreads();   // all reads of h1(t-1)/x complete
        #pragma unroll
        for (int mt = 0; mt < 2; ++mt)
            #pragma unroll
            for (int i = 0; i < 4; ++i)
                #pragma unroll
                for (int r = 0; r < 4; ++r) {
                    float I = sigf(acc[mt][i][0][r]);
                    float F = sigf(acc[mt][i][1][r]);
                    float G = tanhfast(acc[mt][i][2][r]);
                    float O = sigf(acc[mt][i][3][r]);
                    float c = F * c1[mt][i][r] + I * G;
                    c1[mt][i][r] = c;
                    float h = O * tanhfast(c);
                    int m = mt * 16 + quad * 4 + r;
                    int u = (wv * 4 + i) * 16 + nrow;
                    unsigned short hh = f2b(h);
                    h1hi[m * 520 + u] = hh;
                    h1lo[m * 520 + u] = f2b(h - b2f(hh));
                }
        __syncthreads();   // h1(t) visible

        // ================= L2 (k = [relu(h1) 512 ; h2 128], 20 ksteps) =================
        f32x4 a2[2][4];
        #pragma unroll
        for (int mt = 0; mt < 2; ++mt)
            #pragma unroll
            for (int g = 0; g < 4; ++g) {
                float b = b2v[g];
                f32x4 v = {b, b, b, b};
                a2[mt][g] = v;
            }

        #pragma unroll 1
        for (int kk = 0; kk < 20; ++kk) {
            int ks = rev ? (19 - kk) : kk;
            short8 ahi[2], alo[2];
            if (ks < 16) {
                int off = ks * 32 + quad * 8;
                #pragma unroll
                for (int mt = 0; mt < 2; ++mt) {
                    short8 a  = *(const short8*)(h1hi + (mt * 16 + nrow) * 520 + off);
                    short8 al = *(const short8*)(h1lo + (mt * 16 + nrow) * 520 + off);
                    short8 msk = a >> 15;          // per-half: 0xFFFF if negative
                    ahi[mt] = a & ~msk;            // relu on packed hi/lo pair
                    alo[mt] = al & ~msk;
                }
            } else {
                int off = (ks - 16) * 32 + quad * 8;
                ahi[0] = *(const short8*)(h2hi + nrow * 136 + off);
                ahi[1] = *(const short8*)(h2hi + (16 + nrow) * 136 + off);
                alo[0] = *(const short8*)(h2lo + nrow * 136 + off);
                alo[1] = *(const short8*)(h2lo + (16 + nrow) * 136 + off);
            }
            const unsigned short* bb = B2 + ks * 32768;
            #pragma unroll
            for (int g = 0; g < 4; ++g) {
                short8 bhi = *(const short8*)(bb + g * 1024);
                short8 blo = *(const short8*)(bb + g * 1024 + 512);
                #pragma unroll
                for (int mt = 0; mt < 2; ++mt) {
                    a2[mt][g] = __builtin_amdgcn_mfma_f32_16x16x32_bf16(ahi[mt], bhi, a2[mt][g], 0, 0, 0);
                    a2[mt][g] = __builtin_amdgcn_mfma_f32_16x16x32_bf16(alo[mt], bhi, a2[mt][g], 0, 0, 0);
                    a2[mt][g] = __builtin_amdgcn_mfma_f32_16x16x32_bf16(ahi[mt], blo, a2[mt][g], 0, 0, 0);
                }
            }
        }
        __syncthreads();   // reads of h2(t-1) complete
        #pragma unroll
        for (int mt = 0; mt < 2; ++mt)
            #pragma unroll
            for (int r = 0; r < 4; ++r) {
                float I = sigf(a2[mt][0][r]);
                float F = sigf(a2[mt][1][r]);
                float G = tanhfast(a2[mt][2][r]);
                float O = sigf(a2[mt][3][r]);
                float c = F * c2[mt][r] + I * G;
                c2[mt][r] = c;
                float h = O * tanhfast(c);
                int m = mt * 16 + quad * 4 + r;
                int u = wv * 16 + nrow;
                unsigned short hh = f2b(h);
                h2hi[m * 136 + u] = hh;
                h2lo[m * 136 + u] = f2b(h - b2f(hh));
            }
        __syncthreads();   // h2(t) visible

        // ================= L3 (k = [relu(h2) 128 ; h3 64], 6 ksteps) =================
        f32x4 a3[4];
        #pragma unroll
        for (int g = 0; g < 4; ++g) {
            float b = b3v[g];
            f32x4 v = {b, b, b, b};
            a3[g] = v;
        }

        #pragma unroll 1
        for (int kk = 0; kk < 6; ++kk) {
            int ks = rev ? (5 - kk) : kk;
            short8 ahi, alo;
            if (ks < 4) {
                int off = ks * 32 + quad * 8;
                short8 a  = *(const short8*)(h2hi + (mt3 * 16 + nrow) * 136 + off);
                short8 al = *(const short8*)(h2lo + (mt3 * 16 + nrow) * 136 + off);
                short8 msk = a >> 15;
                ahi = a & ~msk;
                alo = al & ~msk;
            } else {
                int off = (ks - 4) * 32 + quad * 8;
                ahi = *(const short8*)(h3hi + (mt3 * 16 + nrow) * 72 + off);
                alo = *(const short8*)(h3lo + (mt3 * 16 + nrow) * 72 + off);
            }
            const unsigned short* bb = B3 + ks * 16384;
            #pragma unroll
            for (int g = 0; g < 4; ++g) {
                short8 bhi = *(const short8*)(bb + g * 1024);
                short8 blo = *(const short8*)(bb + g * 1024 + 512);
                a3[g] = __builtin_amdgcn_mfma_f32_16x16x32_bf16(ahi, bhi, a3[g], 0, 0, 0);
                a3[g] = __builtin_amdgcn_mfma_f32_16x16x32_bf16(alo, bhi, a3[g], 0, 0, 0);
                a3[g] = __builtin_amdgcn_mfma_f32_16x16x32_bf16(ahi, blo, a3[g], 0, 0, 0);
            }
        }
        __syncthreads();   // reads of h3(t-1) complete
        #pragma unroll
        for (int r = 0; r < 4; ++r) {
            float I = sigf(a3[0][r]);
            float F = sigf(a3[1][r]);
            float G = tanhfast(a3[2][r]);
            float O = sigf(a3[3][r]);
            float c = F * c3[r] + I * G;
            c3[r] = c;
            float h = O * tanhfast(c);
            int m = mt3 * 16 + quad * 4 + r;
            int u = (wv & 3) * 16 + nrow;
            unsigned short hh = f2b(h);
            h3hi[m * 72 + u] = hh;
            h3lo[m * 72 + u] = f2b(h - b2f(hh));
            Y3[(size_t)(gr0 + m) * 1920 + t * 64 + u] = fmaxf(h, 0.0f);
        }
        __syncthreads();   // h3(t) visible before next step
    }
}

// FC head: d = |Y3[b] - Y3[b+4096]| (1920) -> 960 -> 480 -> 16 -> 1
#define BTH 4
__global__ __launch_bounds__(256) void head_kernel(
    const float* __restrict__ Y3,
    const float* __restrict__ Wf1, const float* __restrict__ bf1,
    const float* __restrict__ Wf2, const float* __restrict__ bf2,
    const float* __restrict__ Wf3, const float* __restrict__ bf3,
    const float* __restrict__ Wf4, const float* __restrict__ bf4,
    float* __restrict__ out)
{
    __shared__ __align__(16) float ds[BTH][1924];
    __shared__ __align__(16) float a1[BTH][964];
    __shared__ __align__(16) float a2[BTH][484];
    __shared__ __align__(16) float a3[BTH][16];

    const int tid = threadIdx.x;
    const int r0  = blockIdx.x * BTH;

    for (int e = tid; e < BTH * 1920; e += 256) {
        const int b = e / 1920;
        const int j = e - b * 1920;
        const float v1 = Y3[(size_t)(r0 + b) * 1920 + j];
        const float v2 = Y3[(size_t)(r0 + b + NB) * 1920 + j];
        ds[b][j] = fabsf(v1 - v2);
    }
    __syncthreads();

    const int lb = tid & (BTH - 1);
    const int og = tid >> 2;

    for (int m = 0; m < 15; ++m) {
        const int o = og + 64 * m;
        float acc = bf1[o];
        const float4* wr = (const float4*)(Wf1 + (size_t)o * 1920);
        const float4* dv = (const float4*)(&ds[lb][0]);
        #pragma unroll 4
        for (int kc = 0; kc < 480; ++kc) {
            const float4 d4 = dv[kc];
            const float4 w4 = wr[kc];
            acc += d4.x * w4.x + d4.y * w4.y + d4.z * w4.z + d4.w * w4.w;
        }
        a1[lb][o] = fmaxf(acc, 0.0f);
    }
    __syncthreads();

    for (int m = 0; m < 8; ++m) {
        const int o = og + 64 * m;
        if (o < 480) {
            float acc = bf2[o];
            const float4* wr = (const float4*)(Wf2 + (size_t)o * 960);
            const float4* av = (const float4*)(&a1[lb][0]);
            #pragma unroll 4
            for (int kc = 0; kc < 240; ++kc) {
                const float4 d4 = av[kc];
                const float4 w4 = wr[kc];
                acc += d4.x * w4.x + d4.y * w4.y + d4.z * w4.z + d4.w * w4.w;
            }
            a2[lb][o] = fmaxf(acc, 0.0f);
        }
    }
    __syncthreads();

    if (tid < 64) {
        const int o = tid >> 2;
        const int b = tid & (BTH - 1);
        float acc = bf3[o];
        const float4* wr = (const float4*)(Wf3 + (size_t)o * 480);
        const float4* av = (const float4*)(&a2[b][0]);
        #pragma unroll 4
        for (int kc = 0; kc < 120; ++kc) {
            const float4 d4 = av[kc];
            const float4 w4 = wr[kc];
            acc += d4.x * w4.x + d4.y * w4.y + d4.z * w4.z + d4.w * w4.w;
        }
        a3[b][o] = fmaxf(acc, 0.0f);
    }
    __syncthreads();

    if (tid < BTH) {
        float acc = bf4[0];
        #pragma unroll
        for (int k = 0; k < 16; ++k) acc += a3[tid][k] * Wf4[k];
        out[r0 + tid] = acc;
    }
}

extern "C" void kernel_launch(void* const* d_in, const int* in_sizes, int n_in,
                              void* d_out, int out_size, void* d_ws, size_t ws_size,
                              hipStream_t stream) {
    const float* x1   = (const float*)d_in[0];
    const float* x2   = (const float*)d_in[1];
    const float* Wih1 = (const float*)d_in[2];
    const float* Whh1 = (const float*)d_in[3];
    const float* b1   = (const float*)d_in[4];
    const float* Wih2 = (const float*)d_in[5];
    const float* Whh2 = (const float*)d_in[6];
    const float* b2   = (const float*)d_in[7];
    const float* Wih3 = (const float*)d_in[8];
    const float* Whh3 = (const float*)d_in[9];
    const float* b3   = (const float*)d_in[10];
    const float* Wf1  = (const float*)d_in[11];
    const float* bf1  = (const float*)d_in[12];
    const float* Wf2  = (const float*)d_in[13];
    const float* bf2  = (const float*)d_in[14];
    const float* Wf3  = (const float*)d_in[15];
    const float* bf3  = (const float*)d_in[16];
    const float* Wf4  = (const float*)d_in[17];
    const float* bf4  = (const float*)d_in[18];

    float* wsf = (float*)d_ws;
    float* Y3 = wsf;                                      // 8192*30*64 = 15,728,640 f32
    unsigned short* l1w = (unsigned short*)(wsf + 15728640);   // 18*32*4*2*512 = 2,359,296 us
    unsigned short* l2w = l1w + 2359296;                       // 20*8*4*2*512  =   655,360 us
    unsigned short* l3w = l2w + 655360;                        //  6*4*4*2*512  =    98,304 us
    float* out = (float*)d_out;

    // weight packing (bf16 hi/lo, MFMA B-fragment order)
    prep_w<<<(2359296 + 255) / 256, 256, 0, stream>>>(Wih1, Whh1, l1w, 512, 58, 64, 512, 32, 18);
    prep_w<<<(655360  + 255) / 256, 256, 0, stream>>>(Wih2, Whh2, l2w, 128, 512, 512, 128, 8, 20);
    prep_w<<<(98304   + 255) / 256, 256, 0, stream>>>(Wih3, Whh3, l3w, 64, 128, 128, 64, 4, 6);

    hipFuncSetAttribute((const void*)lstm3_mfma,
                        hipFuncAttributeMaxDynamicSharedMemorySize, 102400);
    lstm3_mfma<<<256, 512, 102400, stream>>>(x1, x2, l1w, l2w, l3w, b1, b2, b3, Y3);
    head_kernel<<<NB / BTH, 256, 0, stream>>>(Y3, Wf1, bf1, Wf2, bf2,
                                              Wf3, bf3, Wf4, bf4, out);
}